// Round 1
// baseline (250.884 us; speedup 1.0000x reference)
//
#include <hip/hip_runtime.h>
#include <math.h>

// ---- problem constants ----
#define B 8
#define NWD 32
#define NHD 32
#define NBOX 1024          // NWD*NHD
#define ZWD 8
#define ZID 32
#define KOBJ 48
#define CFEAT 32
#define WRAW 128
#define HRAW 128
#define CR 28
#define CR2 784
#define FAN 25088          // CFEAT*CR2
#define KB 384             // KOBJ*B

// ---- output offsets (floats, concatenated in reference return order) ----
#define OFF_PROB   0
#define OFF_AREA   8192
#define OFF_CFEW   16384
#define OFF_PFEW   16768
#define OFF_BXF    17152
#define OFF_BYF    17536
#define OFF_BWF    17920
#define OFF_BHF    18304
#define OFF_BMASK  18688
#define OFF_BMASKN 6310144
#define OFF_BIMG   12601600
#define OFF_ZWS    18893056
#define OFF_ZWK    18896128
#define OFF_ZIS    18899200
#define OFF_ZIK    18911488

// ---- workspace offsets (floats) ----
#define WS_BX 0
#define WS_BY 8192
#define WS_BW 16384
#define WS_BH 24576
#define WS_ENCP 32768                      // FSPLIT*KB*64 = 393216
#define WS_SMALL (32768 + 16*384*64)       // 425984; size KB*1568 = 602112

// ---- enc GEMM tiling ----
#define FSPLIT 16
#define FCHUNK 112
#define NCHUNK 14          // 14*112 = 1568 = FAN/FSPLIT
#define KBT 16

__device__ __forceinline__ float sigm(float x){ return 1.0f/(1.0f+expf(-x)); }
__device__ __forceinline__ float softpl(float x){ return fmaxf(x,0.0f) + log1pf(expf(-fabsf(x))); }

__device__ __forceinline__ float fetch0(const float* img, int Wd, int Hd, int xi, int yi){
  if (xi < 0 || xi >= Wd || yi < 0 || yi >= Hd) return 0.0f;
  return img[xi*Hd + yi];
}
__device__ __forceinline__ float bilin(const float* img, int Wd, int Hd, float x, float y){
  float x0f = floorf(x), y0f = floorf(y);
  int x0 = (int)x0f, y0 = (int)y0f;
  float wx1 = x - x0f, wx0 = 1.0f - wx1;
  float wy1 = y - y0f, wy0 = 1.0f - wy1;
  return fetch0(img,Wd,Hd,x0,  y0  )*(wx0*wy0) + fetch0(img,Wd,Hd,x0+1,y0  )*(wx1*wy0)
       + fetch0(img,Wd,Hd,x0,  y0+1)*(wx0*wy1) + fetch0(img,Wd,Hd,x0+1,y0+1)*(wx1*wy1);
}

// K1: zwhere reparam + tmaps (1x1 conv + sigmoid) -> bx/by/bw/bh maps + prob/area outputs
__global__ __launch_bounds__(256) void maps_kernel(
    const float* __restrict__ logit, const float* __restrict__ zmu,
    const float* __restrict__ zstd, const float* __restrict__ zeps,
    const float* __restrict__ wz, const float* __restrict__ bz,
    float* __restrict__ out, float* __restrict__ ws){
  int t = blockIdx.x*256 + threadIdx.x;
  if (t >= B*NBOX) return;
  int b = t / NBOX, n = t % NBOX;
  int w = n / NHD, h = n % NHD;
  float acc0=bz[0], acc1=bz[1], acc2=bz[2], acc3=bz[3];
  #pragma unroll
  for(int z=0; z<ZWD; z++){
    int id = ((b*ZWD + z)*NWD + w)*NHD + h;
    float s = zmu[id] + zstd[id]*zeps[id];
    acc0 += s*wz[0*ZWD+z]; acc1 += s*wz[1*ZWD+z];
    acc2 += s*wz[2*ZWD+z]; acc3 += s*wz[3*ZWD+z];
  }
  float tx=sigm(acc0), ty=sigm(acc1), tw=sigm(acc2), th=sigm(acc3);
  float bx = (128.0f*((float)w + tx))/32.0f;
  float by = (128.0f*((float)h + ty))/32.0f;
  float bwv = 10.0f + 30.0f*tw;
  float bhv = 10.0f + 30.0f*th;
  ws[WS_BX + b*NBOX + n] = bx;
  ws[WS_BY + b*NBOX + n] = by;
  ws[WS_BW + b*NBOX + n] = bwv;
  ws[WS_BH + b*NBOX + n] = bhv;
  float lg = logit[t];
  out[OFF_PROB + t] = sigm(lg);
  out[OFF_AREA + t] = bwv*bhv;
}

// K2: per-batch top-48 (desc, ties -> lower index) + gather of all "few" outputs
__global__ __launch_bounds__(256) void topk_kernel(
    const float* __restrict__ logit, const float* __restrict__ zmu,
    const float* __restrict__ zstd, const float* __restrict__ zeps,
    const float* __restrict__ ws, float* __restrict__ out){
  const int b = blockIdx.x;
  const int tid = threadIdx.x;
  __shared__ float vals[NBOX];
  __shared__ float rv[256];
  __shared__ int   ri[256];
  __shared__ int   sel[KOBJ];
  for(int n=tid; n<NBOX; n+=256) vals[n] = logit[b*NBOX + n];
  __syncthreads();
  for(int it=0; it<KOBJ; it++){
    float bv = -INFINITY; int bi = NBOX;
    for(int n=tid; n<NBOX; n+=256){
      float v = vals[n];
      if (v > bv){ bv = v; bi = n; }     // ascending scan => earliest index kept on tie
    }
    rv[tid]=bv; ri[tid]=bi;
    __syncthreads();
    for(int s=128; s>0; s>>=1){
      if (tid < s){
        float ov = rv[tid+s]; int oi = ri[tid+s];
        float mv = rv[tid];   int mi = ri[tid];
        if (ov > mv || (ov == mv && oi < mi)){ rv[tid]=ov; ri[tid]=oi; }
      }
      __syncthreads();
    }
    if (tid == 0){ sel[it] = ri[0]; vals[ri[0]] = -INFINITY; }
    __syncthreads();
  }
  for(int i=tid; i<KOBJ; i+=256){
    int n = sel[i];
    float c = logit[b*NBOX + n];
    out[OFF_CFEW + i*B + b] = c;
    out[OFF_PFEW + i*B + b] = sigm(c);
    out[OFF_BXF  + i*B + b] = ws[WS_BX + b*NBOX + n];
    out[OFF_BYF  + i*B + b] = ws[WS_BY + b*NBOX + n];
    out[OFF_BWF  + i*B + b] = ws[WS_BW + b*NBOX + n];
    out[OFF_BHF  + i*B + b] = ws[WS_BH + b*NBOX + n];
    int w = n / NHD, h = n % NHD;
    #pragma unroll
    for(int z=0; z<ZWD; z++){
      int id = ((b*ZWD + z)*NWD + w)*NHD + h;
      float mu = zmu[id], sd = zstd[id];
      out[OFF_ZWS + (i*B+b)*ZWD + z] = mu + sd*zeps[id];
      out[OFF_ZWK + (i*B+b)*ZWD + z] = 0.5f*(mu*mu + sd*sd) - logf(sd) - 0.5f;
    }
  }
}

// K3: fused crop (bilinear from features) + enc GEMM partials.
// block = (kb-group of 16) x (f-split of 1568); writes partial sums to ws.
__global__ __launch_bounds__(256) void enc_kernel(
    const float* __restrict__ feat, const float* __restrict__ wenc,
    const float* __restrict__ outc, float* __restrict__ ws){
  __shared__ float wl[FCHUNK*65];          // [ff][d], stride 65 -> conflict-free
  __shared__ float cl[KBT*(FCHUNK+1)];     // [rr][ff], stride 113
  __shared__ float rbx[KBT], rby[KBT], rbw[KBT], rbh[KBT];
  const int tid = threadIdx.x;
  const int kbg = blockIdx.x / FSPLIT;
  const int fs  = blockIdx.x % FSPLIT;
  const int kb0 = kbg*KBT;
  if (tid < KBT){
    rbx[tid] = outc[OFF_BXF + kb0 + tid];
    rby[tid] = outc[OFF_BYF + kb0 + tid];
    rbw[tid] = outc[OFF_BWF + kb0 + tid];
    rbh[tid] = outc[OFF_BHF + kb0 + tid];
  }
  __syncthreads();
  const int d  = tid & 63;
  const int r0 = (tid >> 6) * 4;
  float a0=0.f, a1=0.f, a2=0.f, a3=0.f;
  for(int ch=0; ch<NCHUNK; ch++){
    const int fbase = fs*1568 + ch*FCHUNK;
    for(int idx=tid; idx<64*FCHUNK; idx+=256){
      int dd = idx / FCHUNK, ff = idx % FCHUNK;
      wl[ff*65 + dd] = wenc[(size_t)dd*FAN + fbase + ff];
    }
    for(int idx=tid; idx<KBT*FCHUNK; idx+=256){
      int rr = idx / FCHUNK, ff = idx % FCHUNK;
      int f = fbase + ff;
      int c = f / CR2, p = f % CR2;
      int i = p / CR, j = p % CR;
      int kb = kb0 + rr;
      int bb = kb & (B-1);
      float bwv = rbw[rr], bhv = rbh[rr];
      float x = (rbx[rr] - 0.5f*bwv) + ((i+0.5f)/(float)CR)*bwv - 0.5f;
      float y = (rby[rr] - 0.5f*bhv) + ((j+0.5f)/(float)CR)*bhv - 0.5f;
      cl[rr*(FCHUNK+1) + ff] =
          bilin(feat + (size_t)(bb*CFEAT + c)*(WRAW*HRAW), WRAW, HRAW, x, y);
    }
    __syncthreads();
    #pragma unroll 4
    for(int ff=0; ff<FCHUNK; ff++){
      float wv = wl[ff*65 + d];
      a0 += cl[(r0+0)*(FCHUNK+1)+ff]*wv;
      a1 += cl[(r0+1)*(FCHUNK+1)+ff]*wv;
      a2 += cl[(r0+2)*(FCHUNK+1)+ff]*wv;
      a3 += cl[(r0+3)*(FCHUNK+1)+ff]*wv;
    }
    __syncthreads();
  }
  float* dst = ws + WS_ENCP + (size_t)fs*KB*64;
  dst[(kb0+r0+0)*64 + d] = a0;
  dst[(kb0+r0+1)*64 + d] = a1;
  dst[(kb0+r0+2)*64 + d] = a2;
  dst[(kb0+r0+3)*64 + d] = a3;
}

// K4: reduce enc partials + bias, then zi reparam + KL
__global__ __launch_bounds__(64) void zi_kernel(
    const float* __restrict__ ws, const float* __restrict__ benc,
    const float* __restrict__ ieps, float* __restrict__ out){
  int kb = blockIdx.x, d = threadIdx.x;
  float s = benc[d];
  for(int f=0; f<FSPLIT; f++) s += ws[WS_ENCP + ((size_t)f*KB + kb)*64 + d];
  __shared__ float enc[64];
  enc[d] = s;
  __syncthreads();
  if (d < ZID){
    float mu = enc[d];
    float sd = softpl(enc[ZID + d]) + 1e-4f;
    float zs = mu + sd*ieps[kb*ZID + d];
    out[OFF_ZIS + kb*ZID + d] = zs;
    out[OFF_ZIK + kb*ZID + d] = 0.5f*(mu*mu + sd*sd) - logf(sd) - 0.5f;
  }
}

// K5: dec GEMM (32-dot) + softplus/sigmoid + scale by c_few -> ws_small
__global__ __launch_bounds__(256) void dec_kernel(
    const float* __restrict__ outc, const float* __restrict__ wdec,
    const float* __restrict__ bdec, float* __restrict__ ws){
  int kb = blockIdx.x;
  __shared__ float zs[ZID];
  if (threadIdx.x < ZID) zs[threadIdx.x] = outc[OFF_ZIS + kb*ZID + threadIdx.x];
  __syncthreads();
  float cf = outc[OFF_CFEW + kb];
  for(int f=threadIdx.x; f<2*CR2; f+=256){
    float a = bdec[f];
    #pragma unroll
    for(int z=0; z<ZID; z++) a += zs[z]*wdec[f*ZID + z];
    float s = (f < CR2) ? softpl(a) : sigm(a);
    ws[WS_SMALL + (size_t)kb*(2*CR2) + f] = s*cf;
  }
}

// K6: uncrop (bilinear from 28x28, zero outside) -> raw weight into big_mask slot, img into big_img
__global__ __launch_bounds__(256) void uncrop_kernel(
    const float* __restrict__ ws, const float* __restrict__ outc, float* __restrict__ out){
  int kb = blockIdx.x;
  __shared__ float sm[2*CR2];
  for(int t=threadIdx.x; t<2*CR2; t+=256) sm[t] = ws[WS_SMALL + (size_t)kb*(2*CR2) + t];
  __syncthreads();
  float bx = outc[OFF_BXF + kb], by = outc[OFF_BYF + kb];
  float bwv = outc[OFF_BWF + kb], bhv = outc[OFF_BHF + kb];
  for(int p=threadIdx.x; p<WRAW*HRAW; p+=256){
    int X = p >> 7, Y = p & 127;
    float x = (((float)X + 0.5f) - (bx - 0.5f*bwv)) / bwv * (float)CR - 0.5f;
    float y = (((float)Y + 0.5f) - (by - 0.5f*bhv)) / bhv * (float)CR - 0.5f;
    float x0f = floorf(x), y0f = floorf(y);
    int x0 = (int)x0f, y0 = (int)y0f;
    float v0 = 0.f, v1 = 0.f;
    if (!(x0 >= CR || x0+1 < 0 || y0 >= CR || y0+1 < 0)){
      float wx1 = x - x0f, wx0 = 1.0f - wx1;
      float wy1 = y - y0f, wy0 = 1.0f - wy1;
      float w00=wx0*wy0, w10=wx1*wy0, w01=wx0*wy1, w11=wx1*wy1;
      v0 = fetch0(sm,CR,CR,x0,y0)*w00 + fetch0(sm,CR,CR,x0+1,y0)*w10
         + fetch0(sm,CR,CR,x0,y0+1)*w01 + fetch0(sm,CR,CR,x0+1,y0+1)*w11;
      const float* s1 = sm + CR2;
      v1 = fetch0(s1,CR,CR,x0,y0)*w00 + fetch0(s1,CR,CR,x0+1,y0)*w10
         + fetch0(s1,CR,CR,x0,y0+1)*w01 + fetch0(s1,CR,CR,x0+1,y0+1)*w11;
    }
    out[OFF_BMASK + (size_t)kb*16384 + p] = v0;
    out[OFF_BIMG  + (size_t)kb*16384 + p] = v1;
  }
}

// K7: mask composition over k (reads raw weights from big_mask slot, overwrites with final)
__global__ __launch_bounds__(256) void compose_kernel(float* __restrict__ out){
  int t = blockIdx.x*256 + threadIdx.x;       // b*16384 + p
  if (t >= B*16384) return;
  int b = t >> 14, p = t & 16383;
  float wr[KOBJ];
  float sum = 0.f;
  #pragma unroll
  for(int k=0; k<KOBJ; k++){
    float v = out[OFF_BMASK + (size_t)(k*B + b)*16384 + p];
    wr[k] = v; sum += v;
  }
  float th = tanhf(sum);
  float inv = 1.0f / fmaxf(sum, 1e-6f);
  #pragma unroll
  for(int k=0; k<KOBJ; k++){
    size_t o = (size_t)(k*B + b)*16384 + p;
    out[OFF_BMASK  + o] = th * (wr[k] * inv);
    out[OFF_BMASKN + o] = tanhf(wr[k]);
  }
}

extern "C" void kernel_launch(void* const* d_in, const int* in_sizes, int n_in,
                              void* d_out, int out_size, void* d_ws, size_t ws_size,
                              hipStream_t stream) {
  (void)in_sizes; (void)n_in; (void)out_size; (void)ws_size;
  const float* logit = (const float*)d_in[0];
  const float* zmu   = (const float*)d_in[1];
  const float* zstd  = (const float*)d_in[2];
  const float* zeps  = (const float*)d_in[3];
  const float* ieps  = (const float*)d_in[4];
  const float* feat  = (const float*)d_in[5];
  const float* wz    = (const float*)d_in[6];
  const float* bz    = (const float*)d_in[7];
  const float* wenc  = (const float*)d_in[8];
  const float* benc  = (const float*)d_in[9];
  const float* wdec  = (const float*)d_in[10];
  const float* bdec  = (const float*)d_in[11];
  float* out = (float*)d_out;
  float* ws  = (float*)d_ws;

  maps_kernel   <<<(B*NBOX)/256, 256, 0, stream>>>(logit, zmu, zstd, zeps, wz, bz, out, ws);
  topk_kernel   <<<B, 256, 0, stream>>>(logit, zmu, zstd, zeps, ws, out);
  enc_kernel    <<<(KB/KBT)*FSPLIT, 256, 0, stream>>>(feat, wenc, out, ws);
  zi_kernel     <<<KB, 64, 0, stream>>>(ws, benc, ieps, out);
  dec_kernel    <<<KB, 256, 0, stream>>>(out, wdec, bdec, ws);
  uncrop_kernel <<<KB, 256, 0, stream>>>(ws, out, out);
  compose_kernel<<<(B*WRAW*HRAW)/256, 256, 0, stream>>>(out);
}

// Round 2
// 176.702 us; speedup vs baseline: 1.4198x; 1.4198x over previous
//
#include <hip/hip_runtime.h>
#include <math.h>

// ---- problem constants ----
#define B 8
#define NWD 32
#define NHD 32
#define NBOX 1024          // NWD*NHD
#define ZWD 8
#define ZID 32
#define KOBJ 48
#define CFEAT 32
#define WRAW 128
#define HRAW 128
#define CR 28
#define CR2 784
#define FAN 25088          // CFEAT*CR2
#define KB 384             // KOBJ*B

// ---- output offsets (floats, concatenated in reference return order) ----
#define OFF_PROB   0
#define OFF_AREA   8192
#define OFF_CFEW   16384
#define OFF_PFEW   16768
#define OFF_BXF    17152
#define OFF_BYF    17536
#define OFF_BWF    17920
#define OFF_BHF    18304
#define OFF_BMASK  18688
#define OFF_BMASKN 6310144
#define OFF_BIMG   12601600
#define OFF_ZWS    18893056
#define OFF_ZWK    18896128
#define OFF_ZIS    18899200
#define OFF_ZIK    18911488

// ---- workspace offsets (floats) ----
#define WS_BX 0
#define WS_BY 8192
#define WS_BW 16384
#define WS_BH 24576
#define WS_SMALL 32768                     // KB*1568 = 602112 floats

// ---- enc GEMM tiling (v2) ----
// block tile: 32 kb x 64 d, thread tile 4 kb x 2 d; K split into 112 pieces of 224.
// Partials are stashed in the big_mask output region (overwritten later by uncrop).
#define FSPLIT 112
#define FPB 224
#define FCH 56
#define NCH 4
#define MKB 32
#define WL_S 66            // [ff][dd] stride (even -> b64-aligned)
#define CL_S 60            // [rr][ff] stride (mult of 4 -> b128-aligned)

__device__ __forceinline__ float sigm(float x){ return 1.0f/(1.0f+expf(-x)); }
__device__ __forceinline__ float softpl(float x){ return fmaxf(x,0.0f) + log1pf(expf(-fabsf(x))); }

__device__ __forceinline__ float fetch0(const float* img, int Wd, int Hd, int xi, int yi){
  if (xi < 0 || xi >= Wd || yi < 0 || yi >= Hd) return 0.0f;
  return img[xi*Hd + yi];
}

// K1: zwhere reparam + tmaps (1x1 conv + sigmoid) -> bx/by/bw/bh maps + prob/area outputs
__global__ __launch_bounds__(256) void maps_kernel(
    const float* __restrict__ logit, const float* __restrict__ zmu,
    const float* __restrict__ zstd, const float* __restrict__ zeps,
    const float* __restrict__ wz, const float* __restrict__ bz,
    float* __restrict__ out, float* __restrict__ ws){
  int t = blockIdx.x*256 + threadIdx.x;
  if (t >= B*NBOX) return;
  int b = t / NBOX, n = t % NBOX;
  int w = n / NHD, h = n % NHD;
  float acc0=bz[0], acc1=bz[1], acc2=bz[2], acc3=bz[3];
  #pragma unroll
  for(int z=0; z<ZWD; z++){
    int id = ((b*ZWD + z)*NWD + w)*NHD + h;
    float s = zmu[id] + zstd[id]*zeps[id];
    acc0 += s*wz[0*ZWD+z]; acc1 += s*wz[1*ZWD+z];
    acc2 += s*wz[2*ZWD+z]; acc3 += s*wz[3*ZWD+z];
  }
  float tx=sigm(acc0), ty=sigm(acc1), tw=sigm(acc2), th=sigm(acc3);
  float bx = (128.0f*((float)w + tx))/32.0f;
  float by = (128.0f*((float)h + ty))/32.0f;
  float bwv = 10.0f + 30.0f*tw;
  float bhv = 10.0f + 30.0f*th;
  ws[WS_BX + b*NBOX + n] = bx;
  ws[WS_BY + b*NBOX + n] = by;
  ws[WS_BW + b*NBOX + n] = bwv;
  ws[WS_BH + b*NBOX + n] = bhv;
  float lg = logit[t];
  out[OFF_PROB + t] = sigm(lg);
  out[OFF_AREA + t] = bwv*bhv;
}

// K2: per-batch top-48 (desc, ties -> lower index) + gather of all "few" outputs
__global__ __launch_bounds__(256) void topk_kernel(
    const float* __restrict__ logit, const float* __restrict__ zmu,
    const float* __restrict__ zstd, const float* __restrict__ zeps,
    const float* __restrict__ ws, float* __restrict__ out){
  const int b = blockIdx.x;
  const int tid = threadIdx.x;
  __shared__ float vals[NBOX];
  __shared__ float rv[256];
  __shared__ int   ri[256];
  __shared__ int   sel[KOBJ];
  for(int n=tid; n<NBOX; n+=256) vals[n] = logit[b*NBOX + n];
  __syncthreads();
  for(int it=0; it<KOBJ; it++){
    float bv = -INFINITY; int bi = NBOX;
    for(int n=tid; n<NBOX; n+=256){
      float v = vals[n];
      if (v > bv){ bv = v; bi = n; }
    }
    rv[tid]=bv; ri[tid]=bi;
    __syncthreads();
    for(int s=128; s>0; s>>=1){
      if (tid < s){
        float ov = rv[tid+s]; int oi = ri[tid+s];
        float mv = rv[tid];   int mi = ri[tid];
        if (ov > mv || (ov == mv && oi < mi)){ rv[tid]=ov; ri[tid]=oi; }
      }
      __syncthreads();
    }
    if (tid == 0){ sel[it] = ri[0]; vals[ri[0]] = -INFINITY; }
    __syncthreads();
  }
  for(int i=tid; i<KOBJ; i+=256){
    int n = sel[i];
    float c = logit[b*NBOX + n];
    out[OFF_CFEW + i*B + b] = c;
    out[OFF_PFEW + i*B + b] = sigm(c);
    out[OFF_BXF  + i*B + b] = ws[WS_BX + b*NBOX + n];
    out[OFF_BYF  + i*B + b] = ws[WS_BY + b*NBOX + n];
    out[OFF_BWF  + i*B + b] = ws[WS_BW + b*NBOX + n];
    out[OFF_BHF  + i*B + b] = ws[WS_BH + b*NBOX + n];
    int w = n / NHD, h = n % NHD;
    #pragma unroll
    for(int z=0; z<ZWD; z++){
      int id = ((b*ZWD + z)*NWD + w)*NHD + h;
      float mu = zmu[id], sd = zstd[id];
      out[OFF_ZWS + (i*B+b)*ZWD + z] = mu + sd*zeps[id];
      out[OFF_ZWK + (i*B+b)*ZWD + z] = 0.5f*(mu*mu + sd*sd) - logf(sd) - 0.5f;
    }
  }
}

// K3 (v2): fused crop + enc GEMM partials. 1344 blocks, register tiling 4kb x 2d.
__global__ __launch_bounds__(256) void enc_kernel(
    const float* __restrict__ feat, const float* __restrict__ wenc,
    const float* __restrict__ outc, float* __restrict__ part){
  __shared__ float wl[FCH*WL_S];          // [ff][dd]
  __shared__ float cl[MKB*CL_S];          // [rr][ff]
  __shared__ float rAx[MKB], rSx[MKB], rAy[MKB], rSy[MKB];
  const int tid = threadIdx.x;
  const int fs  = blockIdx.x % FSPLIT;
  const int kb0 = (blockIdx.x / FSPLIT) * MKB;
  if (tid < MKB){
    float bx = outc[OFF_BXF + kb0 + tid];
    float by = outc[OFF_BYF + kb0 + tid];
    float bw = outc[OFF_BWF + kb0 + tid];
    float bh = outc[OFF_BHF + kb0 + tid];
    float sx = bw * (1.0f/(float)CR), sy = bh * (1.0f/(float)CR);
    rSx[tid] = sx; rSy[tid] = sy;
    rAx[tid] = bx - 0.5f*bw + 0.5f*sx - 0.5f;
    rAy[tid] = by - 0.5f*bh + 0.5f*sy - 0.5f;
  }
  __syncthreads();
  const int col = tid & 31;
  const int row = tid >> 5;
  const int d0  = col*2;
  float acc[4][2] = {{0.f,0.f},{0.f,0.f},{0.f,0.f},{0.f,0.f}};
  const int f0 = fs*FPB;
  for (int ch = 0; ch < NCH; ch++){
    const int fc0 = f0 + ch*FCH;
    // stage weights: 64 d x 56 ff
    #pragma unroll
    for (int u = 0; u < 14; u++){
      int idx = tid + u*256;
      int dd = idx / FCH, ff = idx - dd*FCH;
      wl[ff*WL_S + dd] = wenc[(size_t)dd*FAN + fc0 + ff];
    }
    // stage crop samples: 32 kb x 56 ff
    #pragma unroll
    for (int u = 0; u < 7; u++){
      int idx = tid + u*256;
      int rr = idx / FCH, ff = idx - rr*FCH;
      int f = fc0 + ff;
      int c = f / CR2; int p = f - c*CR2;
      int i = p / CR;  int j = p - i*CR;
      int kb = kb0 + rr;
      const float* img = feat + (size_t)((kb & (B-1))*CFEAT + c)*(WRAW*HRAW);
      float x = fmaf((float)i, rSx[rr], rAx[rr]);
      float y = fmaf((float)j, rSy[rr], rAy[rr]);
      float x0f = floorf(x), y0f = floorf(y);
      int x0 = (int)x0f, y0 = (int)y0f;
      float wx1 = x - x0f, wx0 = 1.0f - wx1;
      float wy1 = y - y0f, wy0 = 1.0f - wy1;
      if ((unsigned)x0     >= WRAW) wx0 = 0.f;
      if ((unsigned)(x0+1) >= WRAW) wx1 = 0.f;
      if ((unsigned)y0     >= HRAW) wy0 = 0.f;
      if ((unsigned)(y0+1) >= HRAW) wy1 = 0.f;
      int x0c = min(max(x0,0),WRAW-1), x1c = min(max(x0+1,0),WRAW-1);
      int y0c = min(max(y0,0),HRAW-1), y1c = min(max(y0+1,0),HRAW-1);
      const float* r0p = img + x0c*HRAW;
      const float* r1p = img + x1c*HRAW;
      float v = (r0p[y0c]*wy0 + r0p[y1c]*wy1)*wx0
              + (r1p[y0c]*wy0 + r1p[y1c]*wy1)*wx1;
      cl[rr*CL_S + ff] = v;
    }
    __syncthreads();
    #pragma unroll
    for (int ff = 0; ff < FCH; ff += 4){
      float2 w0 = *(const float2*)&wl[(ff+0)*WL_S + d0];
      float2 w1 = *(const float2*)&wl[(ff+1)*WL_S + d0];
      float2 w2 = *(const float2*)&wl[(ff+2)*WL_S + d0];
      float2 w3 = *(const float2*)&wl[(ff+3)*WL_S + d0];
      #pragma unroll
      for (int t = 0; t < 4; t++){
        float4 c4 = *(const float4*)&cl[(row*4+t)*CL_S + ff];
        acc[t][0] = fmaf(c4.x, w0.x, acc[t][0]);
        acc[t][1] = fmaf(c4.x, w0.y, acc[t][1]);
        acc[t][0] = fmaf(c4.y, w1.x, acc[t][0]);
        acc[t][1] = fmaf(c4.y, w1.y, acc[t][1]);
        acc[t][0] = fmaf(c4.z, w2.x, acc[t][0]);
        acc[t][1] = fmaf(c4.z, w2.y, acc[t][1]);
        acc[t][0] = fmaf(c4.w, w3.x, acc[t][0]);
        acc[t][1] = fmaf(c4.w, w3.y, acc[t][1]);
      }
    }
    __syncthreads();
  }
  float* dst = part + ((size_t)fs*KB + kb0)*64;
  #pragma unroll
  for (int t = 0; t < 4; t++){
    int kb = row*4 + t;
    *(float2*)&dst[kb*64 + d0] = make_float2(acc[t][0], acc[t][1]);
  }
}

// K4: reduce enc partials (from big_mask scratch region) + bias, zi reparam + KL
__global__ __launch_bounds__(256) void zi_kernel(
    const float* __restrict__ part, const float* __restrict__ benc,
    const float* __restrict__ ieps, float* __restrict__ out){
  int kb = blockIdx.x;
  int d = threadIdx.x & 63, seg = threadIdx.x >> 6;
  float s = 0.f;
  for (int f = seg; f < FSPLIT; f += 4)
    s += part[((size_t)f*KB + kb)*64 + d];
  __shared__ float red[4][64];
  red[seg][d] = s;
  __syncthreads();
  if (threadIdx.x < ZID){
    int dd = threadIdx.x;
    float mu = benc[dd]     + red[0][dd]     + red[1][dd]     + red[2][dd]     + red[3][dd];
    float pe = benc[ZID+dd] + red[0][ZID+dd] + red[1][ZID+dd] + red[2][ZID+dd] + red[3][ZID+dd];
    float sd = softpl(pe) + 1e-4f;
    float zs = mu + sd*ieps[kb*ZID + dd];
    out[OFF_ZIS + kb*ZID + dd] = zs;
    out[OFF_ZIK + kb*ZID + dd] = 0.5f*(mu*mu + sd*sd) - logf(sd) - 0.5f;
  }
}

// K5: dec GEMM (32-dot) + softplus/sigmoid + scale by c_few -> ws_small
__global__ __launch_bounds__(256) void dec_kernel(
    const float* __restrict__ outc, const float* __restrict__ wdec,
    const float* __restrict__ bdec, float* __restrict__ ws){
  int kb = blockIdx.x;
  __shared__ float zs[ZID];
  if (threadIdx.x < ZID) zs[threadIdx.x] = outc[OFF_ZIS + kb*ZID + threadIdx.x];
  __syncthreads();
  float cf = outc[OFF_CFEW + kb];
  for(int f=threadIdx.x; f<2*CR2; f+=256){
    float a = bdec[f];
    #pragma unroll
    for(int z=0; z<ZID; z++) a += zs[z]*wdec[f*ZID + z];
    float s = (f < CR2) ? softpl(a) : sigm(a);
    ws[WS_SMALL + (size_t)kb*(2*CR2) + f] = s*cf;
  }
}

// K6: uncrop (bilinear from 28x28, zero outside) -> raw weight into big_mask slot, img into big_img
__global__ __launch_bounds__(256) void uncrop_kernel(
    const float* __restrict__ ws, const float* __restrict__ outc, float* __restrict__ out){
  int kb = blockIdx.x;
  __shared__ float sm[2*CR2];
  for(int t=threadIdx.x; t<2*CR2; t+=256) sm[t] = ws[WS_SMALL + (size_t)kb*(2*CR2) + t];
  __syncthreads();
  float bx = outc[OFF_BXF + kb], by = outc[OFF_BYF + kb];
  float bwv = outc[OFF_BWF + kb], bhv = outc[OFF_BHF + kb];
  for(int p=threadIdx.x; p<WRAW*HRAW; p+=256){
    int X = p >> 7, Y = p & 127;
    float x = (((float)X + 0.5f) - (bx - 0.5f*bwv)) / bwv * (float)CR - 0.5f;
    float y = (((float)Y + 0.5f) - (by - 0.5f*bhv)) / bhv * (float)CR - 0.5f;
    float x0f = floorf(x), y0f = floorf(y);
    int x0 = (int)x0f, y0 = (int)y0f;
    float v0 = 0.f, v1 = 0.f;
    if (!(x0 >= CR || x0+1 < 0 || y0 >= CR || y0+1 < 0)){
      float wx1 = x - x0f, wx0 = 1.0f - wx1;
      float wy1 = y - y0f, wy0 = 1.0f - wy1;
      float w00=wx0*wy0, w10=wx1*wy0, w01=wx0*wy1, w11=wx1*wy1;
      v0 = fetch0(sm,CR,CR,x0,y0)*w00 + fetch0(sm,CR,CR,x0+1,y0)*w10
         + fetch0(sm,CR,CR,x0,y0+1)*w01 + fetch0(sm,CR,CR,x0+1,y0+1)*w11;
      const float* s1 = sm + CR2;
      v1 = fetch0(s1,CR,CR,x0,y0)*w00 + fetch0(s1,CR,CR,x0+1,y0)*w10
         + fetch0(s1,CR,CR,x0,y0+1)*w01 + fetch0(s1,CR,CR,x0+1,y0+1)*w11;
    }
    out[OFF_BMASK + (size_t)kb*16384 + p] = v0;
    out[OFF_BIMG  + (size_t)kb*16384 + p] = v1;
  }
}

// K7: mask composition over k (reads raw weights from big_mask slot, overwrites with final)
__global__ __launch_bounds__(256) void compose_kernel(float* __restrict__ out){
  int t = blockIdx.x*256 + threadIdx.x;       // b*16384 + p
  if (t >= B*16384) return;
  int b = t >> 14, p = t & 16383;
  float wr[KOBJ];
  float sum = 0.f;
  #pragma unroll
  for(int k=0; k<KOBJ; k++){
    float v = out[OFF_BMASK + (size_t)(k*B + b)*16384 + p];
    wr[k] = v; sum += v;
  }
  float th = tanhf(sum);
  float inv = 1.0f / fmaxf(sum, 1e-6f);
  #pragma unroll
  for(int k=0; k<KOBJ; k++){
    size_t o = (size_t)(k*B + b)*16384 + p;
    out[OFF_BMASK  + o] = th * (wr[k] * inv);
    out[OFF_BMASKN + o] = tanhf(wr[k]);
  }
}

extern "C" void kernel_launch(void* const* d_in, const int* in_sizes, int n_in,
                              void* d_out, int out_size, void* d_ws, size_t ws_size,
                              hipStream_t stream) {
  (void)in_sizes; (void)n_in; (void)out_size; (void)ws_size;
  const float* logit = (const float*)d_in[0];
  const float* zmu   = (const float*)d_in[1];
  const float* zstd  = (const float*)d_in[2];
  const float* zeps  = (const float*)d_in[3];
  const float* ieps  = (const float*)d_in[4];
  const float* feat  = (const float*)d_in[5];
  const float* wz    = (const float*)d_in[6];
  const float* bz    = (const float*)d_in[7];
  const float* wenc  = (const float*)d_in[8];
  const float* benc  = (const float*)d_in[9];
  const float* wdec  = (const float*)d_in[10];
  const float* bdec  = (const float*)d_in[11];
  float* out = (float*)d_out;
  float* ws  = (float*)d_ws;
  float* part = out + OFF_BMASK;   // 2.75M floats scratch inside big_mask region (6.29M), overwritten by uncrop

  maps_kernel   <<<(B*NBOX)/256, 256, 0, stream>>>(logit, zmu, zstd, zeps, wz, bz, out, ws);
  topk_kernel   <<<B, 256, 0, stream>>>(logit, zmu, zstd, zeps, ws, out);
  enc_kernel    <<<(KB/MKB)*FSPLIT, 256, 0, stream>>>(feat, wenc, out, part);
  zi_kernel     <<<KB, 256, 0, stream>>>(part, benc, ieps, out);
  dec_kernel    <<<KB, 256, 0, stream>>>(out, wdec, bdec, ws);
  uncrop_kernel <<<KB, 256, 0, stream>>>(ws, out, out);
  compose_kernel<<<(B*WRAW*HRAW)/256, 256, 0, stream>>>(out);
}

// Round 3
// 132.734 us; speedup vs baseline: 1.8901x; 1.3312x over previous
//
#include <hip/hip_runtime.h>
#include <math.h>

// ---- problem constants ----
#define B 8
#define NWD 32
#define NHD 32
#define NBOX 1024          // NWD*NHD
#define ZWD 8
#define ZID 32
#define KOBJ 48
#define CFEAT 32
#define WRAW 128
#define HRAW 128
#define CR 28
#define CR2 784
#define FAN 25088          // CFEAT*CR2
#define KB 384             // KOBJ*B

// ---- output offsets (floats, concatenated in reference return order) ----
#define OFF_PROB   0
#define OFF_AREA   8192
#define OFF_CFEW   16384
#define OFF_PFEW   16768
#define OFF_BXF    17152
#define OFF_BYF    17536
#define OFF_BWF    17920
#define OFF_BHF    18304
#define OFF_BMASK  18688
#define OFF_BMASKN 6310144
#define OFF_BIMG   12601600
#define OFF_ZWS    18893056
#define OFF_ZWK    18896128
#define OFF_ZIS    18899200
#define OFF_ZIK    18911488

// ---- workspace offsets (floats) ----
#define WS_SMALL 32768                     // KB*1568 = 602112 floats

// ---- enc GEMM tiling ----
#define FSPLIT 112
#define FPB 224
#define FCH 56
#define NCH 4
#define MKB 32
#define WL_S 66            // [ff][dd] stride
#define CL_S 60            // [rr][ff] stride

__device__ __forceinline__ float sigm(float x){ return 1.0f/(1.0f+expf(-x)); }
__device__ __forceinline__ float softpl(float x){ return fmaxf(x,0.0f) + log1pf(expf(-fabsf(x))); }

__device__ __forceinline__ float fetch0(const float* img, int Wd, int Hd, int xi, int yi){
  if (xi < 0 || xi >= Wd || yi < 0 || yi >= Hd) return 0.0f;
  return img[xi*Hd + yi];
}
__device__ __forceinline__ unsigned okey(float f){
  unsigned b = __float_as_uint(f);
  return b ^ ((b & 0x80000000u) ? 0xFFFFFFFFu : 0x80000000u);  // monotone: bigger float -> bigger uint
}

// K1 (fused): maps + single-pass rank-based top-48 + gather of all "few" outputs.
// grid = B*4 blocks of 256; block (b, sb) owns elements n in [sb*256, sb*256+256).
__global__ __launch_bounds__(256) void maps_topk_kernel(
    const float* __restrict__ logit, const float* __restrict__ zmu,
    const float* __restrict__ zstd, const float* __restrict__ zeps,
    const float* __restrict__ wz, const float* __restrict__ bz,
    float* __restrict__ out){
  const int b  = blockIdx.x >> 2;
  const int sb = blockIdx.x & 3;
  const int tid = threadIdx.x;
  __shared__ unsigned su[NBOX];
  #pragma unroll
  for (int u = 0; u < 4; u++){
    int j = tid + u*256;
    su[j] = okey(logit[b*NBOX + j]);
  }
  const int n = sb*256 + tid;
  const int w = n >> 5, h = n & 31;
  // box params for my element
  float acc0=bz[0], acc1=bz[1], acc2=bz[2], acc3=bz[3];
  #pragma unroll
  for(int z=0; z<ZWD; z++){
    int id = ((b*ZWD + z)*NWD + w)*NHD + h;
    float s = zmu[id] + zstd[id]*zeps[id];
    acc0 += s*wz[0*ZWD+z]; acc1 += s*wz[1*ZWD+z];
    acc2 += s*wz[2*ZWD+z]; acc3 += s*wz[3*ZWD+z];
  }
  float tx=sigm(acc0), ty=sigm(acc1), tw=sigm(acc2), th=sigm(acc3);
  float bx = (128.0f*((float)w + tx))/32.0f;
  float by = (128.0f*((float)h + ty))/32.0f;
  float bwv = 10.0f + 30.0f*tw;
  float bhv = 10.0f + 30.0f*th;
  float lg = logit[b*NBOX + n];
  out[OFF_PROB + b*NBOX + n] = sigm(lg);
  out[OFF_AREA + b*NBOX + n] = bwv*bhv;
  __syncthreads();
  // rank = #{j : (u_j > u_i) || (u_j == u_i && j < i)}
  const unsigned ui = su[n];
  int rank = 0;
  #pragma unroll 8
  for (int j = 0; j < NBOX; j++){
    unsigned uj = su[j];
    rank += (uj > ui || (uj == ui && j < n)) ? 1 : 0;
  }
  if (rank < KOBJ){
    out[OFF_CFEW + rank*B + b] = lg;
    out[OFF_PFEW + rank*B + b] = sigm(lg);
    out[OFF_BXF  + rank*B + b] = bx;
    out[OFF_BYF  + rank*B + b] = by;
    out[OFF_BWF  + rank*B + b] = bwv;
    out[OFF_BHF  + rank*B + b] = bhv;
    #pragma unroll
    for(int z=0; z<ZWD; z++){
      int id = ((b*ZWD + z)*NWD + w)*NHD + h;
      float mu = zmu[id], sd = zstd[id];
      out[OFF_ZWS + (rank*B+b)*ZWD + z] = mu + sd*zeps[id];
      out[OFF_ZWK + (rank*B+b)*ZWD + z] = 0.5f*(mu*mu + sd*sd) - logf(sd) - 0.5f;
    }
  }
}

// K3: fused crop + enc GEMM partials. 1344 blocks, register tiling 4kb x 2d.
__global__ __launch_bounds__(256) void enc_kernel(
    const float* __restrict__ feat, const float* __restrict__ wenc,
    const float* __restrict__ outc, float* __restrict__ part){
  __shared__ float wl[FCH*WL_S];          // [ff][dd]
  __shared__ float cl[MKB*CL_S];          // [rr][ff]
  __shared__ float rAx[MKB], rSx[MKB], rAy[MKB], rSy[MKB];
  const int tid = threadIdx.x;
  const int fs  = blockIdx.x % FSPLIT;
  const int kb0 = (blockIdx.x / FSPLIT) * MKB;
  if (tid < MKB){
    float bx = outc[OFF_BXF + kb0 + tid];
    float by = outc[OFF_BYF + kb0 + tid];
    float bw = outc[OFF_BWF + kb0 + tid];
    float bh = outc[OFF_BHF + kb0 + tid];
    float sx = bw * (1.0f/(float)CR), sy = bh * (1.0f/(float)CR);
    rSx[tid] = sx; rSy[tid] = sy;
    rAx[tid] = bx - 0.5f*bw + 0.5f*sx - 0.5f;
    rAy[tid] = by - 0.5f*bh + 0.5f*sy - 0.5f;
  }
  __syncthreads();
  const int col = tid & 31;
  const int row = tid >> 5;
  const int d0  = col*2;
  float acc[4][2] = {{0.f,0.f},{0.f,0.f},{0.f,0.f},{0.f,0.f}};
  const int f0 = fs*FPB;
  for (int ch = 0; ch < NCH; ch++){
    const int fc0 = f0 + ch*FCH;
    #pragma unroll
    for (int u = 0; u < 14; u++){
      int idx = tid + u*256;
      int dd = idx / FCH, ff = idx - dd*FCH;
      wl[ff*WL_S + dd] = wenc[(size_t)dd*FAN + fc0 + ff];
    }
    #pragma unroll
    for (int u = 0; u < 7; u++){
      int idx = tid + u*256;
      int rr = idx / FCH, ff = idx - rr*FCH;
      int f = fc0 + ff;
      int c = f / CR2; int p = f - c*CR2;
      int i = p / CR;  int j = p - i*CR;
      int kb = kb0 + rr;
      const float* img = feat + (size_t)((kb & (B-1))*CFEAT + c)*(WRAW*HRAW);
      float x = fmaf((float)i, rSx[rr], rAx[rr]);
      float y = fmaf((float)j, rSy[rr], rAy[rr]);
      float x0f = floorf(x), y0f = floorf(y);
      int x0 = (int)x0f, y0 = (int)y0f;
      float wx1 = x - x0f, wx0 = 1.0f - wx1;
      float wy1 = y - y0f, wy0 = 1.0f - wy1;
      if ((unsigned)x0     >= WRAW) wx0 = 0.f;
      if ((unsigned)(x0+1) >= WRAW) wx1 = 0.f;
      if ((unsigned)y0     >= HRAW) wy0 = 0.f;
      if ((unsigned)(y0+1) >= HRAW) wy1 = 0.f;
      int x0c = min(max(x0,0),WRAW-1), x1c = min(max(x0+1,0),WRAW-1);
      int y0c = min(max(y0,0),HRAW-1), y1c = min(max(y0+1,0),HRAW-1);
      const float* r0p = img + x0c*HRAW;
      const float* r1p = img + x1c*HRAW;
      float v = (r0p[y0c]*wy0 + r0p[y1c]*wy1)*wx0
              + (r1p[y0c]*wy0 + r1p[y1c]*wy1)*wx1;
      cl[rr*CL_S + ff] = v;
    }
    __syncthreads();
    #pragma unroll
    for (int ff = 0; ff < FCH; ff += 4){
      float2 w0 = *(const float2*)&wl[(ff+0)*WL_S + d0];
      float2 w1 = *(const float2*)&wl[(ff+1)*WL_S + d0];
      float2 w2 = *(const float2*)&wl[(ff+2)*WL_S + d0];
      float2 w3 = *(const float2*)&wl[(ff+3)*WL_S + d0];
      #pragma unroll
      for (int t = 0; t < 4; t++){
        float4 c4 = *(const float4*)&cl[(row*4+t)*CL_S + ff];
        acc[t][0] = fmaf(c4.x, w0.x, acc[t][0]);
        acc[t][1] = fmaf(c4.x, w0.y, acc[t][1]);
        acc[t][0] = fmaf(c4.y, w1.x, acc[t][0]);
        acc[t][1] = fmaf(c4.y, w1.y, acc[t][1]);
        acc[t][0] = fmaf(c4.z, w2.x, acc[t][0]);
        acc[t][1] = fmaf(c4.z, w2.y, acc[t][1]);
        acc[t][0] = fmaf(c4.w, w3.x, acc[t][0]);
        acc[t][1] = fmaf(c4.w, w3.y, acc[t][1]);
      }
    }
    __syncthreads();
  }
  float* dst = part + ((size_t)fs*KB + kb0)*64;
  #pragma unroll
  for (int t = 0; t < 4; t++){
    int kb = row*4 + t;
    *(float2*)&dst[kb*64 + d0] = make_float2(acc[t][0], acc[t][1]);
  }
}

// K4: reduce enc partials + bias, zi reparam + KL
__global__ __launch_bounds__(256) void zi_kernel(
    const float* __restrict__ part, const float* __restrict__ benc,
    const float* __restrict__ ieps, float* __restrict__ out){
  int kb = blockIdx.x;
  int d = threadIdx.x & 63, seg = threadIdx.x >> 6;
  float s = 0.f;
  for (int f = seg; f < FSPLIT; f += 4)
    s += part[((size_t)f*KB + kb)*64 + d];
  __shared__ float red[4][64];
  red[seg][d] = s;
  __syncthreads();
  if (threadIdx.x < ZID){
    int dd = threadIdx.x;
    float mu = benc[dd]     + red[0][dd]     + red[1][dd]     + red[2][dd]     + red[3][dd];
    float pe = benc[ZID+dd] + red[0][ZID+dd] + red[1][ZID+dd] + red[2][ZID+dd] + red[3][ZID+dd];
    float sd = softpl(pe) + 1e-4f;
    float zs = mu + sd*ieps[kb*ZID + dd];
    out[OFF_ZIS + kb*ZID + dd] = zs;
    out[OFF_ZIK + kb*ZID + dd] = 0.5f*(mu*mu + sd*sd) - logf(sd) - 0.5f;
  }
}

// K5: dec GEMM (32-dot) + softplus/sigmoid + scale by c_few -> ws_small
__global__ __launch_bounds__(256) void dec_kernel(
    const float* __restrict__ outc, const float* __restrict__ wdec,
    const float* __restrict__ bdec, float* __restrict__ ws){
  int kb = blockIdx.x;
  __shared__ float zs[ZID];
  if (threadIdx.x < ZID) zs[threadIdx.x] = outc[OFF_ZIS + kb*ZID + threadIdx.x];
  __syncthreads();
  float cf = outc[OFF_CFEW + kb];
  for(int f=threadIdx.x; f<2*CR2; f+=256){
    float a = bdec[f];
    #pragma unroll
    for(int z=0; z<ZID; z++) a += zs[z]*wdec[f*ZID + z];
    float s = (f < CR2) ? softpl(a) : sigm(a);
    ws[WS_SMALL + (size_t)kb*(2*CR2) + f] = s*cf;
  }
}

// K6: uncrop -> raw weight into big_mask slot, img into big_img
__global__ __launch_bounds__(256) void uncrop_kernel(
    const float* __restrict__ ws, const float* __restrict__ outc, float* __restrict__ out){
  int kb = blockIdx.x;
  __shared__ float sm[2*CR2];
  for(int t=threadIdx.x; t<2*CR2; t+=256) sm[t] = ws[WS_SMALL + (size_t)kb*(2*CR2) + t];
  __syncthreads();
  float bx = outc[OFF_BXF + kb], by = outc[OFF_BYF + kb];
  float bwv = outc[OFF_BWF + kb], bhv = outc[OFF_BHF + kb];
  for(int p=threadIdx.x; p<WRAW*HRAW; p+=256){
    int X = p >> 7, Y = p & 127;
    float x = (((float)X + 0.5f) - (bx - 0.5f*bwv)) / bwv * (float)CR - 0.5f;
    float y = (((float)Y + 0.5f) - (by - 0.5f*bhv)) / bhv * (float)CR - 0.5f;
    float x0f = floorf(x), y0f = floorf(y);
    int x0 = (int)x0f, y0 = (int)y0f;
    float v0 = 0.f, v1 = 0.f;
    if (!(x0 >= CR || x0+1 < 0 || y0 >= CR || y0+1 < 0)){
      float wx1 = x - x0f, wx0 = 1.0f - wx1;
      float wy1 = y - y0f, wy0 = 1.0f - wy1;
      float w00=wx0*wy0, w10=wx1*wy0, w01=wx0*wy1, w11=wx1*wy1;
      v0 = fetch0(sm,CR,CR,x0,y0)*w00 + fetch0(sm,CR,CR,x0+1,y0)*w10
         + fetch0(sm,CR,CR,x0,y0+1)*w01 + fetch0(sm,CR,CR,x0+1,y0+1)*w11;
      const float* s1 = sm + CR2;
      v1 = fetch0(s1,CR,CR,x0,y0)*w00 + fetch0(s1,CR,CR,x0+1,y0)*w10
         + fetch0(s1,CR,CR,x0,y0+1)*w01 + fetch0(s1,CR,CR,x0+1,y0+1)*w11;
    }
    out[OFF_BMASK + (size_t)kb*16384 + p] = v0;
    out[OFF_BIMG  + (size_t)kb*16384 + p] = v1;
  }
}

// K7: mask composition over k
__global__ __launch_bounds__(256) void compose_kernel(float* __restrict__ out){
  int t = blockIdx.x*256 + threadIdx.x;       // b*16384 + p
  if (t >= B*16384) return;
  int b = t >> 14, p = t & 16383;
  float wr[KOBJ];
  float sum = 0.f;
  #pragma unroll
  for(int k=0; k<KOBJ; k++){
    float v = out[OFF_BMASK + (size_t)(k*B + b)*16384 + p];
    wr[k] = v; sum += v;
  }
  float th = tanhf(sum);
  float inv = 1.0f / fmaxf(sum, 1e-6f);
  #pragma unroll
  for(int k=0; k<KOBJ; k++){
    size_t o = (size_t)(k*B + b)*16384 + p;
    out[OFF_BMASK  + o] = th * (wr[k] * inv);
    out[OFF_BMASKN + o] = tanhf(wr[k]);
  }
}

extern "C" void kernel_launch(void* const* d_in, const int* in_sizes, int n_in,
                              void* d_out, int out_size, void* d_ws, size_t ws_size,
                              hipStream_t stream) {
  (void)in_sizes; (void)n_in; (void)out_size; (void)ws_size;
  const float* logit = (const float*)d_in[0];
  const float* zmu   = (const float*)d_in[1];
  const float* zstd  = (const float*)d_in[2];
  const float* zeps  = (const float*)d_in[3];
  const float* ieps  = (const float*)d_in[4];
  const float* feat  = (const float*)d_in[5];
  const float* wz    = (const float*)d_in[6];
  const float* bz    = (const float*)d_in[7];
  const float* wenc  = (const float*)d_in[8];
  const float* benc  = (const float*)d_in[9];
  const float* wdec  = (const float*)d_in[10];
  const float* bdec  = (const float*)d_in[11];
  float* out = (float*)d_out;
  float* ws  = (float*)d_ws;
  float* part = out + OFF_BMASK;   // scratch inside big_mask region, overwritten later by uncrop

  maps_topk_kernel<<<B*4, 256, 0, stream>>>(logit, zmu, zstd, zeps, wz, bz, out);
  enc_kernel    <<<(KB/MKB)*FSPLIT, 256, 0, stream>>>(feat, wenc, out, part);
  zi_kernel     <<<KB, 256, 0, stream>>>(part, benc, ieps, out);
  dec_kernel    <<<KB, 256, 0, stream>>>(out, wdec, bdec, ws);
  uncrop_kernel <<<KB, 256, 0, stream>>>(ws, out, out);
  compose_kernel<<<(B*WRAW*HRAW)/256, 256, 0, stream>>>(out);
}

// Round 4
// 100.215 us; speedup vs baseline: 2.5035x; 1.3245x over previous
//
#include <hip/hip_runtime.h>
#include <math.h>

// ---- problem constants ----
#define B 8
#define NWD 32
#define NHD 32
#define NBOX 1024          // NWD*NHD
#define ZWD 8
#define ZID 32
#define KOBJ 48
#define CFEAT 32
#define WRAW 128
#define HRAW 128
#define CR 28
#define CR2 784
#define FAN 25088          // CFEAT*CR2
#define KB 384             // KOBJ*B

// ---- output offsets (floats, concatenated in reference return order) ----
#define OFF_PROB   0
#define OFF_AREA   8192
#define OFF_CFEW   16384
#define OFF_PFEW   16768
#define OFF_BXF    17152
#define OFF_BYF    17536
#define OFF_BWF    17920
#define OFF_BHF    18304
#define OFF_BMASK  18688
#define OFF_BMASKN 6310144
#define OFF_BIMG   12601600
#define OFF_ZWS    18893056
#define OFF_ZWK    18896128
#define OFF_ZIS    18899200
#define OFF_ZIK    18911488

// ---- workspace offsets (floats) ----
#define WS_SMALL 32768                     // KB*1568 = 602112 floats

// ---- enc GEMM tiling (MFMA v3) ----
#define FSPLIT 112
#define FPB 224            // K-slice per block
#define MKB 32             // kb rows per block
#define KSTR 232           // LDS row stride in bf16 elems (464B = 29*16B, conflict-spread)

typedef __attribute__((ext_vector_type(8))) short bfrag;    // 8 bf16 (4 VGPRs)
typedef __attribute__((ext_vector_type(4))) float f32x4;

__device__ __forceinline__ float sigm(float x){ return 1.0f/(1.0f+expf(-x)); }
__device__ __forceinline__ float softpl(float x){ return fmaxf(x,0.0f) + log1pf(expf(-fabsf(x))); }
__device__ __forceinline__ float ftanh(float x){
  float t = __expf(2.0f*x);
  return 1.0f - __fdividef(2.0f, t + 1.0f);   // exact at ±inf, ~1e-6 rel otherwise
}
__device__ __forceinline__ unsigned short f2bf(float f){   // RNE f32->bf16
  unsigned u = __float_as_uint(f);
  unsigned r = u + 0x7FFFu + ((u >> 16) & 1u);
  return (unsigned short)(r >> 16);
}
__device__ __forceinline__ unsigned okey(float f){
  unsigned b = __float_as_uint(f);
  return b ^ ((b & 0x80000000u) ? 0xFFFFFFFFu : 0x80000000u);
}

// K1: maps + single-pass rank-based top-48 + gather of all "few" outputs.
__global__ __launch_bounds__(256) void maps_topk_kernel(
    const float* __restrict__ logit, const float* __restrict__ zmu,
    const float* __restrict__ zstd, const float* __restrict__ zeps,
    const float* __restrict__ wz, const float* __restrict__ bz,
    float* __restrict__ out){
  const int b  = blockIdx.x >> 2;
  const int sb = blockIdx.x & 3;
  const int tid = threadIdx.x;
  __shared__ unsigned su[NBOX];
  #pragma unroll
  for (int u = 0; u < 4; u++){
    int j = tid + u*256;
    su[j] = okey(logit[b*NBOX + j]);
  }
  const int n = sb*256 + tid;
  const int w = n >> 5, h = n & 31;
  float acc0=bz[0], acc1=bz[1], acc2=bz[2], acc3=bz[3];
  #pragma unroll
  for(int z=0; z<ZWD; z++){
    int id = ((b*ZWD + z)*NWD + w)*NHD + h;
    float s = zmu[id] + zstd[id]*zeps[id];
    acc0 += s*wz[0*ZWD+z]; acc1 += s*wz[1*ZWD+z];
    acc2 += s*wz[2*ZWD+z]; acc3 += s*wz[3*ZWD+z];
  }
  float tx=sigm(acc0), ty=sigm(acc1), tw=sigm(acc2), th=sigm(acc3);
  float bx = (128.0f*((float)w + tx))/32.0f;
  float by = (128.0f*((float)h + ty))/32.0f;
  float bwv = 10.0f + 30.0f*tw;
  float bhv = 10.0f + 30.0f*th;
  float lg = logit[b*NBOX + n];
  out[OFF_PROB + b*NBOX + n] = sigm(lg);
  out[OFF_AREA + b*NBOX + n] = bwv*bhv;
  __syncthreads();
  const unsigned ui = su[n];
  int rank = 0;
  #pragma unroll 8
  for (int j = 0; j < NBOX; j++){
    unsigned uj = su[j];
    rank += (uj > ui || (uj == ui && j < n)) ? 1 : 0;
  }
  if (rank < KOBJ){
    out[OFF_CFEW + rank*B + b] = lg;
    out[OFF_PFEW + rank*B + b] = sigm(lg);
    out[OFF_BXF  + rank*B + b] = bx;
    out[OFF_BYF  + rank*B + b] = by;
    out[OFF_BWF  + rank*B + b] = bwv;
    out[OFF_BHF  + rank*B + b] = bhv;
    #pragma unroll
    for(int z=0; z<ZWD; z++){
      int id = ((b*ZWD + z)*NWD + w)*NHD + h;
      float mu = zmu[id], sd = zstd[id];
      out[OFF_ZWS + (rank*B+b)*ZWD + z] = mu + sd*zeps[id];
      out[OFF_ZWK + (rank*B+b)*ZWD + z] = 0.5f*(mu*mu + sd*sd) - logf(sd) - 0.5f;
    }
  }
}

// K2 (v3): fused crop sampling (bf16 LDS) + MFMA GEMM partials.
// block = (kb-group of 32) x (K-slice of 224); 4 waves, each 16kb x 32d.
__global__ __launch_bounds__(256) void enc_kernel(
    const float* __restrict__ feat, const float* __restrict__ wenc,
    const float* __restrict__ outc, float* __restrict__ part){
  __shared__ __align__(16) unsigned short wl[64*KSTR];   // weights [d][k] bf16
  __shared__ __align__(16) unsigned short cl[MKB*KSTR];  // crops  [kb][k] bf16
  __shared__ float rAx[MKB], rSx[MKB], rAy[MKB], rSy[MKB];
  const int tid = threadIdx.x;
  const int fs  = blockIdx.x % FSPLIT;
  const int kb0 = (blockIdx.x / FSPLIT) * MKB;
  if (tid < MKB){
    float bx = outc[OFF_BXF + kb0 + tid];
    float by = outc[OFF_BYF + kb0 + tid];
    float bw = outc[OFF_BWF + kb0 + tid];
    float bh = outc[OFF_BHF + kb0 + tid];
    float sx = bw * (1.0f/(float)CR), sy = bh * (1.0f/(float)CR);
    rSx[tid] = sx; rSy[tid] = sy;
    rAx[tid] = bx - 0.5f*bw + 0.5f*sx - 0.5f;
    rAy[tid] = by - 0.5f*bh + 0.5f*sy - 0.5f;
  }
  __syncthreads();
  const int fc0 = fs*FPB;
  // stage weights: 64 d x 224 k, float4 loads -> bf16x4 packed stores
  #pragma unroll
  for (int u = 0; u < 14; u++){
    int idx = u*256 + tid;
    int dd = idx / 56, q = idx - dd*56;
    float4 w4 = *(const float4*)&wenc[(size_t)dd*FAN + fc0 + q*4];
    unsigned long long pk = (unsigned long long)f2bf(w4.x)
      | ((unsigned long long)f2bf(w4.y) << 16)
      | ((unsigned long long)f2bf(w4.z) << 32)
      | ((unsigned long long)f2bf(w4.w) << 48);
    *(unsigned long long*)&wl[dd*KSTR + q*4] = pk;
  }
  // stage crop samples: 32 kb x 224 k
  #pragma unroll 4
  for (int u = 0; u < 28; u++){
    int idx = u*256 + tid;
    int rr = idx / FPB, ff = idx - rr*FPB;
    int f = fc0 + ff;
    int c = f / CR2; int p = f - c*CR2;
    int i = p / CR;  int j = p - i*CR;
    int kb = kb0 + rr;
    const float* img = feat + (size_t)((kb & (B-1))*CFEAT + c)*(WRAW*HRAW);
    float x = fmaf((float)i, rSx[rr], rAx[rr]);
    float y = fmaf((float)j, rSy[rr], rAy[rr]);
    float x0f = floorf(x), y0f = floorf(y);
    int x0 = (int)x0f, y0 = (int)y0f;
    float wx1 = x - x0f, wx0 = 1.0f - wx1;
    float wy1 = y - y0f, wy0 = 1.0f - wy1;
    if ((unsigned)x0     >= WRAW) wx0 = 0.f;
    if ((unsigned)(x0+1) >= WRAW) wx1 = 0.f;
    if ((unsigned)y0     >= HRAW) wy0 = 0.f;
    if ((unsigned)(y0+1) >= HRAW) wy1 = 0.f;
    int x0c = min(max(x0,0),WRAW-1), x1c = min(max(x0+1,0),WRAW-1);
    int y0c = min(max(y0,0),HRAW-1), y1c = min(max(y0+1,0),HRAW-1);
    const float* r0p = img + x0c*HRAW;
    const float* r1p = img + x1c*HRAW;
    float v = (r0p[y0c]*wy0 + r0p[y1c]*wy1)*wx0
            + (r1p[y0c]*wy0 + r1p[y1c]*wy1)*wx1;
    cl[rr*KSTR + ff] = f2bf(v);
  }
  __syncthreads();
  // MFMA: wave wv handles kb-half h, d-half g (16kb x 32d), 7 k-steps of 32
  const int lane = tid & 63, wv = tid >> 6;
  const int h = wv & 1, g = wv >> 1;
  const int lr = lane & 15, lg = lane >> 4;
  f32x4 acc0 = {0.f,0.f,0.f,0.f}, acc1 = {0.f,0.f,0.f,0.f};
  const unsigned short* arow  = &cl[(h*16 + lr)*KSTR + lg*8];
  const unsigned short* brow0 = &wl[(g*32 + lr)*KSTR + lg*8];
  const unsigned short* brow1 = &wl[(g*32 + 16 + lr)*KSTR + lg*8];
  #pragma unroll
  for (int s = 0; s < 7; s++){
    bfrag a  = *(const bfrag*)(arow  + s*32);
    bfrag b0 = *(const bfrag*)(brow0 + s*32);
    bfrag b1 = *(const bfrag*)(brow1 + s*32);
    acc0 = __builtin_amdgcn_mfma_f32_16x16x32_bf16(a, b0, acc0, 0, 0, 0);
    acc1 = __builtin_amdgcn_mfma_f32_16x16x32_bf16(a, b1, acc1, 0, 0, 0);
  }
  float* dst = part + ((size_t)fs*KB + kb0)*64;
  #pragma unroll
  for (int r = 0; r < 4; r++){
    int row = h*16 + lg*4 + r;
    dst[row*64 + g*32 + lr]      = acc0[r];
    dst[row*64 + g*32 + 16 + lr] = acc1[r];
  }
}

// K3: reduce enc partials + bias -> zi reparam/KL -> dec GEMM + act -> ws_small
__global__ __launch_bounds__(256) void zi_dec_kernel(
    const float* __restrict__ part, const float* __restrict__ benc,
    const float* __restrict__ ieps, const float* __restrict__ wdec,
    const float* __restrict__ bdec, float* __restrict__ out,
    float* __restrict__ ws){
  int kb = blockIdx.x;
  int d = threadIdx.x & 63, seg = threadIdx.x >> 6;
  float s = 0.f;
  for (int f = seg; f < FSPLIT; f += 4)
    s += part[((size_t)f*KB + kb)*64 + d];
  __shared__ float red[4][64];
  __shared__ float zs[ZID];
  __shared__ float cf_s;
  red[seg][d] = s;
  __syncthreads();
  if (threadIdx.x < ZID){
    int dd = threadIdx.x;
    float mu = benc[dd]     + red[0][dd]     + red[1][dd]     + red[2][dd]     + red[3][dd];
    float pe = benc[ZID+dd] + red[0][ZID+dd] + red[1][ZID+dd] + red[2][ZID+dd] + red[3][ZID+dd];
    float sd = softpl(pe) + 1e-4f;
    float zsv = mu + sd*ieps[kb*ZID + dd];
    out[OFF_ZIS + kb*ZID + dd] = zsv;
    out[OFF_ZIK + kb*ZID + dd] = 0.5f*(mu*mu + sd*sd) - logf(sd) - 0.5f;
    zs[dd] = zsv;
  }
  if (threadIdx.x == 0) cf_s = out[OFF_CFEW + kb];
  __syncthreads();
  float cf = cf_s;
  for (int f = threadIdx.x; f < 2*CR2; f += 256){
    float a = bdec[f];
    #pragma unroll
    for (int q = 0; q < 8; q++){
      float4 w4 = *(const float4*)&wdec[f*ZID + q*4];
      a = fmaf(zs[q*4+0], w4.x, a);
      a = fmaf(zs[q*4+1], w4.y, a);
      a = fmaf(zs[q*4+2], w4.z, a);
      a = fmaf(zs[q*4+3], w4.w, a);
    }
    float v = (f < CR2) ? softpl(a) : sigm(a);
    ws[WS_SMALL + (size_t)kb*(2*CR2) + f] = v*cf;
  }
}

// K4: fused uncrop + compose. One thread per (b, pixel); wr[48] in registers.
__global__ __launch_bounds__(256) void uncrop_compose_kernel(
    const float* __restrict__ ws, float* __restrict__ out){
  const int t = blockIdx.x*256 + threadIdx.x;
  const int b = t >> 14, p = t & 16383;
  const int X = p >> 7, Y = p & 127;
  __shared__ float sAx[KOBJ], sSx[KOBJ], sAy[KOBJ], sSy[KOBJ];
  if (threadIdx.x < KOBJ){
    int k = threadIdx.x;
    float bx = out[OFF_BXF + k*B + b], bw = out[OFF_BWF + k*B + b];
    float by = out[OFF_BYF + k*B + b], bh = out[OFF_BHF + k*B + b];
    float ix = __fdividef((float)CR, bw), iy = __fdividef((float)CR, bh);
    sSx[k] = ix; sAx[k] = (0.5f*bw - bx)*ix - 0.5f;
    sSy[k] = iy; sAy[k] = (0.5f*bh - by)*iy - 0.5f;
  }
  __syncthreads();
  const float xc = (float)X + 0.5f, yc = (float)Y + 0.5f;
  float wr[KOBJ];
  float sum = 0.f;
  #pragma unroll
  for (int k = 0; k < KOBJ; k++){
    float x = fmaf(xc, sSx[k], sAx[k]);
    float y = fmaf(yc, sSy[k], sAy[k]);
    const float* sm = ws + WS_SMALL + (size_t)(k*B + b)*(2*CR2);
    float x0f = floorf(x), y0f = floorf(y);
    int x0 = (int)x0f, y0 = (int)y0f;
    float wx1 = x - x0f, wx0 = 1.0f - wx1;
    float wy1 = y - y0f, wy0 = 1.0f - wy1;
    if ((unsigned)x0     >= CR) wx0 = 0.f;
    if ((unsigned)(x0+1) >= CR) wx1 = 0.f;
    if ((unsigned)y0     >= CR) wy0 = 0.f;
    if ((unsigned)(y0+1) >= CR) wy1 = 0.f;
    int x0c = min(max(x0,0),CR-1), x1c = min(max(x0+1,0),CR-1);
    int y0c = min(max(y0,0),CR-1), y1c = min(max(y0+1,0),CR-1);
    const float* r0 = sm + x0c*CR;
    const float* r1 = sm + x1c*CR;
    float v0 = (r0[y0c]*wy0 + r0[y1c]*wy1)*wx0 + (r1[y0c]*wy0 + r1[y1c]*wy1)*wx1;
    const float* q0 = r0 + CR2;
    const float* q1 = r1 + CR2;
    float v1 = (q0[y0c]*wy0 + q0[y1c]*wy1)*wx0 + (q1[y0c]*wy0 + q1[y1c]*wy1)*wx1;
    wr[k] = v0; sum += v0;
    out[OFF_BIMG + (size_t)(k*B + b)*16384 + p] = v1;
  }
  float th = ftanh(sum);
  float inv = 1.0f / fmaxf(sum, 1e-6f);
  #pragma unroll
  for (int k = 0; k < KOBJ; k++){
    size_t o = (size_t)(k*B + b)*16384 + p;
    out[OFF_BMASK  + o] = th * (wr[k] * inv);
    out[OFF_BMASKN + o] = ftanh(wr[k]);
  }
}

extern "C" void kernel_launch(void* const* d_in, const int* in_sizes, int n_in,
                              void* d_out, int out_size, void* d_ws, size_t ws_size,
                              hipStream_t stream) {
  (void)in_sizes; (void)n_in; (void)out_size; (void)ws_size;
  const float* logit = (const float*)d_in[0];
  const float* zmu   = (const float*)d_in[1];
  const float* zstd  = (const float*)d_in[2];
  const float* zeps  = (const float*)d_in[3];
  const float* ieps  = (const float*)d_in[4];
  const float* feat  = (const float*)d_in[5];
  const float* wz    = (const float*)d_in[6];
  const float* bz    = (const float*)d_in[7];
  const float* wenc  = (const float*)d_in[8];
  const float* benc  = (const float*)d_in[9];
  const float* wdec  = (const float*)d_in[10];
  const float* bdec  = (const float*)d_in[11];
  float* out = (float*)d_out;
  float* ws  = (float*)d_ws;
  float* part = out + OFF_BMASK;   // scratch inside big_mask region (2.75M < 6.29M floats), overwritten later

  maps_topk_kernel    <<<B*4, 256, 0, stream>>>(logit, zmu, zstd, zeps, wz, bz, out);
  enc_kernel          <<<(KB/MKB)*FSPLIT, 256, 0, stream>>>(feat, wenc, out, part);
  zi_dec_kernel       <<<KB, 256, 0, stream>>>(part, benc, ieps, wdec, bdec, out, ws);
  uncrop_compose_kernel<<<(B*WRAW*HRAW)/256, 256, 0, stream>>>(ws, out);
}